// Round 5
// baseline (3588.832 us; speedup 1.0000x reference)
//
#include <hip/hip_runtime.h>
#include <stdint.h>

#define N      12288              // 96*128 descriptors
#define CH     512                // channels
#define NTILE  96                 // N/128
#define NS     8                  // j-slices (grid.y)
#define JT_PER_S 12               // j-tiles per slice

typedef _Float16 f16x8 __attribute__((ext_vector_type(8)));
typedef float    f32x4 __attribute__((ext_vector_type(4)));

struct Top2 { float v0, v1; int i0, i1; };

// ---- module-scope device scratch (graph-capture safe, rewritten every launch)
__device__ float g_invA[N];
__device__ float g_invB[N];
// split-fp16 transposed operands: [d][16 k-groups][8 chunks of 16B] where the
// chunk order within each 128B row is XOR-swizzled by (d&7): chunk c of the
// LOGICAL [32 hi | 32 lo] layout lives at physical chunk c^(d&7).  This makes
// the linear global_load_lds copy produce a bank-conflict-free LDS layout.
__device__ unsigned short g_AT[(size_t)N * 1024];
__device__ unsigned short g_BT[(size_t)N * 1024];
__device__ Top2  g_rpart[NS][N];
__device__ Top2  g_cpart[NTILE][N];
__device__ int   g_nn12[N];
__device__ float g_r12[N];
__device__ float g_sim0[N];
__device__ int   g_nn21[N];
__device__ float g_r21[N];

// insert candidate (v, idx) into running top-2; ties -> lower index (lax.top_k)
__device__ __forceinline__ void t2_ins(float v, int idx,
                                       float& v0, int& i0, float& v1, int& i1) {
  bool beats0 = (v > v0) || (v == v0 && idx < i0);
  bool beats1 = (v > v1) || (v == v1 && idx < i1);
  if (beats0) { v1 = v0; i1 = i0; v0 = v; i0 = idx; }
  else if (beats1) { v1 = v; i1 = idx; }
}

__device__ __forceinline__ float bf16_quant(float f) {
  unsigned int u = __float_as_uint(f);
  unsigned int r = 0x7fffu + ((u >> 16) & 1u);
  unsigned int q = ((u + r) >> 16) << 16;
  return __uint_as_float(q);
}

// async global->LDS, 16 B per lane; LDS dest = wave-uniform base + lane*16
__device__ __forceinline__ void gload16(const void* g, void* lds) {
  __builtin_amdgcn_global_load_lds((const __attribute__((address_space(1))) void*)g,
                                   (__attribute__((address_space(3))) void*)lds,
                                   16, 0, 0);
}

// ---------------- kernel 1: transpose + split-fp16 + inverse norms ----------------
// grid (192, 2): 64 descriptors per block; y=0 -> A, y=1 -> B.
// x' = 1024*x (avoids fp16 subnormals); hi=fp16(x'), lo=fp16(x'-hi).
// Store with per-row chunk swizzle c -> c^(d&7) (see g_AT comment).
__global__ __launch_bounds__(256)
void prep_kernel(const float* __restrict__ A, const float* __restrict__ B) {
  const int d0 = blockIdx.x * 64;
  const float* src = blockIdx.y ? B : A;
  unsigned short* dst = blockIdx.y ? g_BT : g_AT;
  float* inv = blockIdx.y ? g_invB : g_invA;

  __shared__ float Ls[32][68];            // fp32 in-tile (68: 16B-aligned rows)
  __shared__ unsigned short Os[64][64];   // packed out-tile [d][32 hi|32 lo]
  __shared__ float Ps[4][64];             // norm partials

  const int t = threadIdx.x;
  const int a = t >> 6, dl = t & 63;
  float sum = 0.f;

  for (int g = 0; g < 16; ++g) {
    __syncthreads();
    {   // load [32 ch][64 d] fp32 tile, coalesced
      const int c = t >> 3, dc = (t & 7) * 8;
      const float* p = src + (size_t)(g * 32 + c) * N + d0 + dc;
      float4 v0 = *reinterpret_cast<const float4*>(p);
      float4 v1 = *reinterpret_cast<const float4*>(p + 4);
      *reinterpret_cast<float4*>(&Ls[c][dc])     = v0;
      *reinterpret_cast<float4*>(&Ls[c][dc + 4]) = v1;
    }
    __syncthreads();
    {   // split 8 channels per thread, pack into Os
      _Float16 hv[8] __attribute__((aligned(16)));
      _Float16 lv[8] __attribute__((aligned(16)));
#pragma unroll
      for (int j = 0; j < 8; ++j) {
        float v = Ls[a * 8 + j][dl] * 1024.0f;
        sum += v * v;
        _Float16 h = (_Float16)v;
        float rr = v - (float)h;          // exact in fp32
        hv[j] = h;
        lv[j] = (_Float16)rr;
      }
      *reinterpret_cast<uint4*>(&Os[dl][a * 8])      = *reinterpret_cast<const uint4*>(hv);
      *reinterpret_cast<uint4*>(&Os[dl][32 + a * 8]) = *reinterpret_cast<const uint4*>(lv);
    }
    __syncthreads();
    {   // store out-tile: 128 B per descriptor row, chunks XOR-swizzled
#pragma unroll
      for (int p2 = 0; p2 < 2; ++p2) {
        const int d = p2 * 32 + (t >> 3), ch = t & 7;
        const int sc = ch ^ (d & 7);      // swizzled chunk slot
        *reinterpret_cast<uint4*>((char*)(dst + (size_t)(d0 + d) * 1024) + g * 128 + sc * 16)
            = *reinterpret_cast<const uint4*>(&Os[d][ch * 8]);
      }
    }
  }
  Ps[a][dl] = sum;
  __syncthreads();
  if (t < 64) {
    float tot = Ps[0][t] + Ps[1][t] + Ps[2][t] + Ps[3][t];
    inv[d0 + t] = 1.0f / sqrtf(tot);
  }
}

// ---------------- kernel 2: MFMA GEMM + fused dual top-2 ----------------
// grid (96, 8). 128x128 tile, 4 waves, each wave a 64x64 quadrant of 4x4
// 16x16 fragments. DOUBLE-BUFFERED global_load_lds staging (T3/T4 minimum):
// batch for K-step g+1 is issued under the MFMA of K-step g; ONE raw
// s_barrier + one vmcnt(0) (with a full compute phase of slack) per K-step.
// R4's single-buffer 2x-__syncthreads structure exposed full load latency
// per K-step -> 8.5% MfmaUtil. 3-term MFMA: acc += Ah*Bh + Ah*Bl + Al*Bh.
// LDS 74 KB -> 2 blocks/CU; __launch_bounds__(256,2) -> 256-reg cap, no spill.
__global__ __launch_bounds__(256, 2)
void sim_top2_mfma() {
  __shared__ unsigned short SM[2][2][128 * 64]; // [parity][A/B][tile] = 64 KB
  __shared__ Top2 rowW[2][128];            // per-wc row partials (persistent)
  __shared__ Top2 colW[2][128];            // per-wr col partials (per j-tile)
  __shared__ float iaS[128];
  __shared__ float ibS[128];

  const int itile = blockIdx.x, slice = blockIdx.y;
  const int i0 = itile * 128;
  const int tid = threadIdx.x;
  const int wave = tid >> 6, lane = tid & 63;
  const int wr = wave >> 1, wc = wave & 1;
  const int fr = lane & 15, kq = lane >> 4;

  // staging addresses: wave w copies rows w*32+it*8+(lane>>3), chunk lane&7
  const char* gAl = (const char*)g_AT
      + (size_t)(i0 + wave * 32 + (lane >> 3)) * 2048 + (lane & 7) * 16;

  // issue batch for (first j-tile, g=0) into parity 0 as early as possible
  const int jtb = slice * JT_PER_S, jte = jtb + JT_PER_S;
  const char* gBl = (const char*)g_BT
      + (size_t)(jtb * 128 + wave * 32 + (lane >> 3)) * 2048 + (lane & 7) * 16;

  auto stage = [&](int pp, int g_) {
    char* la = (char*)&SM[pp][0][0] + wave * 4096;
    char* lb = (char*)&SM[pp][1][0] + wave * 4096;
    const char* ga = gAl + (size_t)g_ * 128;
    const char* gb = gBl + (size_t)g_ * 128;
#pragma unroll
    for (int it = 0; it < 4; ++it) {
      gload16(ga + (size_t)it * 8 * 2048, la + it * 1024);
      gload16(gb + (size_t)it * 8 * 2048, lb + it * 1024);
    }
  };

  stage(0, 0);                              // prologue batch (j-tile jtb, g=0)

  if (tid < 128) {
    iaS[tid] = g_invA[i0 + tid];
    Top2 z; z.v0 = -1e30f; z.v1 = -1e30f; z.i0 = 0x7fffffff; z.i1 = 0x7fffffff;
    rowW[0][tid] = z; rowW[1][tid] = z;
  }
  __syncthreads();                          // rowW/iaS visible (drains vmcnt; once)

  // loop-invariant LDS fragment byte offsets (logical chunk ^ (row&7))
  const int f7 = fr & 7;
  const int cHi = (kq ^ f7) << 4;
  const int cLo = ((kq + 4) ^ f7) << 4;
  int aOff[4], bOff[4];
#pragma unroll
  for (int mi = 0; mi < 4; ++mi) aOff[mi] = (wr * 64 + mi * 16 + fr) * 128;
#pragma unroll
  for (int ni = 0; ni < 4; ++ni) bOff[ni] = (wc * 64 + ni * 16 + fr) * 128;

  int p = 0;                                // parity: returns to 0 every j-tile

  for (int jt = jtb; jt < jte; ++jt) {
    const int j0 = jt * 128;
    if (tid < 128) ibS[tid] = g_invB[j0 + tid];

    f32x4 acc[4][4];
#pragma unroll
    for (int mi = 0; mi < 4; ++mi)
#pragma unroll
      for (int ni = 0; ni < 4; ++ni)
#pragma unroll
        for (int q = 0; q < 4; ++q) acc[mi][ni][q] = 0.f;

    for (int g = 0; g < 16; ++g) {
      // batch g (issued one K-step ago) complete; all waves past their reads
      asm volatile("s_waitcnt vmcnt(0)" ::: "memory");
      __builtin_amdgcn_s_barrier();
      asm volatile("" ::: "memory");
      if (g < 15) stage(p ^ 1, g + 1);      // next batch rides under the MFMA

      const char* bA = (const char*)&SM[p][0][0];
      const char* bB = (const char*)&SM[p][1][0];
      f16x8 ah[4], al[4];
#pragma unroll
      for (int mi = 0; mi < 4; ++mi) {
        ah[mi] = *reinterpret_cast<const f16x8*>(bA + aOff[mi] + cHi);
        al[mi] = *reinterpret_cast<const f16x8*>(bA + aOff[mi] + cLo);
      }
#pragma unroll
      for (int ni = 0; ni < 4; ++ni) {
        f16x8 bh = *reinterpret_cast<const f16x8*>(bB + bOff[ni] + cHi);
        f16x8 bl = *reinterpret_cast<const f16x8*>(bB + bOff[ni] + cLo);
#pragma unroll
        for (int mi = 0; mi < 4; ++mi) {
          acc[mi][ni] = __builtin_amdgcn_mfma_f32_16x16x32_f16(ah[mi], bh, acc[mi][ni], 0, 0, 0);
          acc[mi][ni] = __builtin_amdgcn_mfma_f32_16x16x32_f16(ah[mi], bl, acc[mi][ni], 0, 0, 0);
          acc[mi][ni] = __builtin_amdgcn_mfma_f32_16x16x32_f16(al[mi], bh, acc[mi][ni], 0, 0, 0);
        }
      }
      asm volatile("" ::: "memory");
      p ^= 1;
    }
    // prefetch next j-tile's g=0 under the top-2 epilogue (~4k cycles of cover).
    // SM[p] was last read at g=14; all waves passed g=15's barrier -> safe.
    if (jt + 1 < jte) {
      gBl = (const char*)g_BT
          + (size_t)((jt + 1) * 128 + wave * 32 + (lane >> 3)) * 2048 + (lane & 7) * 16;
      stage(p, 0);
    }

    // ---- epilogue: scale to cosine sims (C layout: col=fr, row=kq*4+r) ----
    float ib[4];
#pragma unroll
    for (int ni = 0; ni < 4; ++ni) ib[ni] = ibS[wc * 64 + ni * 16 + fr];
#pragma unroll
    for (int mi = 0; mi < 4; ++mi)
#pragma unroll
      for (int r = 0; r < 4; ++r) {
        const float iar = iaS[wr * 64 + mi * 16 + kq * 4 + r];
#pragma unroll
        for (int ni = 0; ni < 4; ++ni)
          acc[mi][ni][r] *= iar * ib[ni];
      }

    // ---- row top-2 (reduce over cols: lanes sharing kq, then ni) ----
#pragma unroll
    for (int mi = 0; mi < 4; ++mi) {
#pragma unroll
      for (int r = 0; r < 4; ++r) {
        const int row = wr * 64 + mi * 16 + kq * 4 + r;
        float v0 = -1e30f, v1 = -1e30f; int id0 = 0x7fffffff, id1 = 0x7fffffff;
#pragma unroll
        for (int ni = 0; ni < 4; ++ni)
          t2_ins(acc[mi][ni][r], j0 + wc * 64 + ni * 16 + fr, v0, id0, v1, id1);
#pragma unroll
        for (int m = 1; m < 16; m <<= 1) {
          float ov0 = __shfl_xor(v0, m), ov1 = __shfl_xor(v1, m);
          int oi0 = __shfl_xor(id0, m), oi1 = __shfl_xor(id1, m);
          t2_ins(ov0, oi0, v0, id0, v1, id1);
          t2_ins(ov1, oi1, v0, id0, v1, id1);
        }
        if (fr == 0) {                     // unique (wave, kq, mi, r) owner
          Top2 tT = rowW[wc][row];
          t2_ins(v0, id0, tT.v0, tT.i0, tT.v1, tT.i1);
          t2_ins(v1, id1, tT.v0, tT.i0, tT.v1, tT.i1);
          rowW[wc][row] = tT;
        }
      }
    }

    // ---- col top-2 (reduce 16 in-thread rows, then across kq groups) ----
#pragma unroll
    for (int ni = 0; ni < 4; ++ni) {
      float v0 = -1e30f, v1 = -1e30f; int id0 = 0x7fffffff, id1 = 0x7fffffff;
#pragma unroll
      for (int mi = 0; mi < 4; ++mi)
#pragma unroll
        for (int r = 0; r < 4; ++r)
          t2_ins(acc[mi][ni][r], i0 + wr * 64 + mi * 16 + kq * 4 + r, v0, id0, v1, id1);
#pragma unroll
      for (int m = 16; m < 64; m <<= 1) {
        float ov0 = __shfl_xor(v0, m), ov1 = __shfl_xor(v1, m);
        int oi0 = __shfl_xor(id0, m), oi1 = __shfl_xor(id1, m);
        t2_ins(ov0, oi0, v0, id0, v1, id1);
        t2_ins(ov1, oi1, v0, id0, v1, id1);
      }
      if (kq == 0) {
        Top2 tT; tT.v0 = v0; tT.v1 = v1; tT.i0 = id0; tT.i1 = id1;
        colW[wr][wc * 64 + ni * 16 + fr] = tT;
      }
    }
    __syncthreads();
    if (tid < 128) {
      Top2 tT = colW[0][tid];
      Top2 o  = colW[1][tid];
      t2_ins(o.v0, o.i0, tT.v0, tT.i0, tT.v1, tT.i1);
      t2_ins(o.v1, o.i1, tT.v0, tT.i0, tT.v1, tT.i1);
      g_cpart[itile][j0 + tid] = tT;
    }
  }

  __syncthreads();
  if (tid < 128) {
    Top2 tT = rowW[0][tid];
    Top2 o  = rowW[1][tid];
    t2_ins(o.v0, o.i0, tT.v0, tT.i0, tT.v1, tT.i1);
    t2_ins(o.v1, o.i1, tT.v0, tT.i0, tT.v1, tT.i1);
    g_rpart[slice][i0 + tid] = tT;
  }
}

// ---------------- kernel 3: merge partials ----------------
__global__ void merge_kernel() {
  int i = blockIdx.x * 256 + threadIdx.x;
  if (i >= N) return;
  {
    float v0 = -1e30f, v1 = -1e30f; int id0 = 0x7fffffff, id1 = 0x7fffffff;
#pragma unroll
    for (int s = 0; s < NS; ++s) {
      Top2 p = g_rpart[s][i];
      t2_ins(p.v0, p.i0, v0, id0, v1, id1);
      t2_ins(p.v1, p.i1, v0, id0, v1, id1);
    }
    float d0 = 2.f - 2.f * v0, d1 = 2.f - 2.f * v1;
    g_nn12[i] = id0; g_r12[i] = d0 / (d1 + 1e-8f); g_sim0[i] = v0;
  }
  {
    float v0 = -1e30f, v1 = -1e30f; int id0 = 0x7fffffff, id1 = 0x7fffffff;
    for (int it = 0; it < NTILE; ++it) {
      Top2 p = g_cpart[it][i];
      t2_ins(p.v0, p.i0, v0, id0, v1, id1);
      t2_ins(p.v1, p.i1, v0, id0, v1, id1);
    }
    float d0 = 2.f - 2.f * v0, d1 = 2.f - 2.f * v1;
    g_nn21[i] = id0; g_r21[i] = d0 / (d1 + 1e-8f);
  }
}

// ---------------- kernel 4: mutual-NN + ratio mask, outputs ----------------
__global__ void finalize_kernel(float* __restrict__ out) {
  int i = blockIdx.x * 256 + threadIdx.x;
  if (i >= N) return;
  int j = g_nn12[i];
  int jc = j < 0 ? 0 : (j >= N ? N - 1 : j);
  bool mask = (g_nn21[jc] == i) && (g_r12[i] <= 0.95f) && (g_r21[jc] <= 0.95f);
  out[i]         = bf16_quant(mask ? g_sim0[i] : 0.f);
  out[N + i]     = bf16_quant((float)j);
  out[2 * N + i] = mask ? 1.f : 0.f;
}

extern "C" void kernel_launch(void* const* d_in, const int* in_sizes, int n_in,
                              void* d_out, int out_size, void* d_ws, size_t ws_size,
                              hipStream_t stream) {
  const float* A = (const float*)d_in[0];  // fp32, channel-major [CH][N]
  const float* B = (const float*)d_in[1];
  (void)d_ws; (void)ws_size;

  prep_kernel<<<dim3(192, 2), 256, 0, stream>>>(A, B);
  sim_top2_mfma<<<dim3(NTILE, NS), 256, 0, stream>>>();
  merge_kernel<<<dim3((N + 255) / 256), 256, 0, stream>>>();
  finalize_kernel<<<dim3((N + 255) / 256), 256, 0, stream>>>((float*)d_out);
}

// Round 6
// 3461.354 us; speedup vs baseline: 1.0368x; 1.0368x over previous
//
#include <hip/hip_runtime.h>
#include <stdint.h>

#define N      12288              // 96*128 descriptors
#define CH     512                // channels
#define NTILE  96                 // N/128
#define NS     8                  // j-slices (grid.y)
#define JT_PER_S 12               // j-tiles per slice
#define NSTEP  (JT_PER_S * 16)    // 192 K-steps per block (12 j-tiles x 16 groups)

typedef _Float16 f16x8 __attribute__((ext_vector_type(8)));
typedef float    f32x4 __attribute__((ext_vector_type(4)));

struct Top2 { float v0, v1; int i0, i1; };

// ---- module-scope device scratch (graph-capture safe, rewritten every launch)
__device__ float g_invA[N];
__device__ float g_invB[N];
// split-fp16 operands, K-MAJOR: [g][d][8 chunks of 16B].  For K-group g the
// 128 descriptors of a tile are a CONTIGUOUS 16 KB stripe -> global_load_lds
// streams 1 KB contiguous per instruction (R4/R5 layout scattered 8x128B).
// Within each 128B row the chunk order is XOR-swizzled: logical chunk c lives
// at physical chunk c^(d&7), so the linear DMA produces bank-conflict-free LDS.
__device__ unsigned short g_AT[(size_t)N * 1024];
__device__ unsigned short g_BT[(size_t)N * 1024];
__device__ Top2  g_rpart[NS][N];
__device__ Top2  g_cpart[NTILE][N];
__device__ int   g_nn12[N];
__device__ float g_r12[N];
__device__ float g_sim0[N];
__device__ int   g_nn21[N];
__device__ float g_r21[N];

// insert candidate (v, idx) into running top-2; ties -> lower index (lax.top_k)
__device__ __forceinline__ void t2_ins(float v, int idx,
                                       float& v0, int& i0, float& v1, int& i1) {
  bool beats0 = (v > v0) || (v == v0 && idx < i0);
  bool beats1 = (v > v1) || (v == v1 && idx < i1);
  if (beats0) { v1 = v0; i1 = i0; v0 = v; i0 = idx; }
  else if (beats1) { v1 = v; i1 = idx; }
}

__device__ __forceinline__ float bf16_quant(float f) {
  unsigned int u = __float_as_uint(f);
  unsigned int r = 0x7fffu + ((u >> 16) & 1u);
  unsigned int q = ((u + r) >> 16) << 16;
  return __uint_as_float(q);
}

// async global->LDS, 16 B per lane; LDS dest = wave-uniform base + lane*16
__device__ __forceinline__ void gload16(const void* g, void* lds) {
  __builtin_amdgcn_global_load_lds((const __attribute__((address_space(1))) void*)g,
                                   (__attribute__((address_space(3))) void*)lds,
                                   16, 0, 0);
}

// ---------------- kernel 1: transpose + split-fp16 + inverse norms ----------------
// grid (192, 2): 64 descriptors per block; y=0 -> A, y=1 -> B.
// x' = 1024*x (avoids fp16 subnormals); hi=fp16(x'), lo=fp16(x'-hi).
// Store K-MAJOR with per-row chunk swizzle c -> c^(d&7) (see g_AT comment).
__global__ __launch_bounds__(256)
void prep_kernel(const float* __restrict__ A, const float* __restrict__ B) {
  const int d0 = blockIdx.x * 64;
  const float* src = blockIdx.y ? B : A;
  unsigned short* dst = blockIdx.y ? g_BT : g_AT;
  float* inv = blockIdx.y ? g_invB : g_invA;

  __shared__ float Ls[32][68];            // fp32 in-tile (68: 16B-aligned rows)
  __shared__ unsigned short Os[64][64];   // packed out-tile [d][32 hi|32 lo]
  __shared__ float Ps[4][64];             // norm partials

  const int t = threadIdx.x;
  const int a = t >> 6, dl = t & 63;
  float sum = 0.f;

  for (int g = 0; g < 16; ++g) {
    __syncthreads();
    {   // load [32 ch][64 d] fp32 tile, coalesced
      const int c = t >> 3, dc = (t & 7) * 8;
      const float* p = src + (size_t)(g * 32 + c) * N + d0 + dc;
      float4 v0 = *reinterpret_cast<const float4*>(p);
      float4 v1 = *reinterpret_cast<const float4*>(p + 4);
      *reinterpret_cast<float4*>(&Ls[c][dc])     = v0;
      *reinterpret_cast<float4*>(&Ls[c][dc + 4]) = v1;
    }
    __syncthreads();
    {   // split 8 channels per thread, pack into Os
      _Float16 hv[8] __attribute__((aligned(16)));
      _Float16 lv[8] __attribute__((aligned(16)));
#pragma unroll
      for (int j = 0; j < 8; ++j) {
        float v = Ls[a * 8 + j][dl] * 1024.0f;
        sum += v * v;
        _Float16 h = (_Float16)v;
        float rr = v - (float)h;          // exact in fp32
        hv[j] = h;
        lv[j] = (_Float16)rr;
      }
      *reinterpret_cast<uint4*>(&Os[dl][a * 8])      = *reinterpret_cast<const uint4*>(hv);
      *reinterpret_cast<uint4*>(&Os[dl][32 + a * 8]) = *reinterpret_cast<const uint4*>(lv);
    }
    __syncthreads();
    {   // store out-tile K-major: row d of group g at ((g*N)+d0+d)*128 bytes
#pragma unroll
      for (int p2 = 0; p2 < 2; ++p2) {
        const int d = p2 * 32 + (t >> 3), ch = t & 7;
        const int sc = ch ^ (d & 7);      // swizzled chunk slot
        *reinterpret_cast<uint4*>((char*)dst
            + ((size_t)g * N + d0 + d) * 128 + sc * 16)
            = *reinterpret_cast<const uint4*>(&Os[d][ch * 8]);
      }
    }
  }
  Ps[a][dl] = sum;
  __syncthreads();
  if (t < 64) {
    float tot = Ps[0][t] + Ps[1][t] + Ps[2][t] + Ps[3][t];
    inv[d0 + t] = 1.0f / sqrtf(tot);
  }
}

// ---------------- kernel 2: MFMA GEMM + fused dual top-2 ----------------
// grid (96, 8). 128x128 tile, 4 waves, each a 64x64 quadrant of 4x4 16x16
// fragments.  COUNTED-VMCNT double-buffer pipeline (T3/T4), continuous over
// all 192 K-steps:
//   step t: B1 (all waves done reading buf[(t+1)&1])
//           stage(t+1) -> buf[(t+1)&1]            (8 global_load_lds)
//           s_waitcnt vmcnt(8)                     (batch t landed; t+1 flies)
//           B2 (everyone's batch t landed) ; MFMA from buf[t&1]
// The in-flight batch spans the barriers and the whole compute phase, so no
// K-step exposes load latency (R4/R5 drained vmcnt(0) per step -> 8% MfmaUtil).
// 3-term split-fp16 MFMA: acc += Ah*Bh + Ah*Bl + Al*Bh (bit-identical result).
__global__ __launch_bounds__(256, 2)
void sim_top2_mfma() {
  __shared__ unsigned short SM[2][2][128 * 64]; // [parity][A/B][tile] = 64 KB
  __shared__ Top2 rowW[2][128];            // per-wc row partials (persistent)
  __shared__ Top2 colW[2][128];            // per-wr col partials (per j-tile)
  __shared__ float iaS[128];
  __shared__ float ibS[128];

  const int itile = blockIdx.x, slice = blockIdx.y;
  const int i0 = itile * 128;
  const int tid = threadIdx.x;
  const int wave = tid >> 6, lane = tid & 63;
  const int wr = wave >> 1, wc = wave & 1;
  const int fr = lane & 15, kq = lane >> 4;
  const int jtb = slice * JT_PER_S;

  // staging: wave w copies bytes [w*4096, w*4096+4096) of the 16 KB stripe
  const int wOff = wave * 4096;
  const int gOff = wOff + lane * 16;       // global adds per-lane 16B

  auto stage = [&](int t) {                // t = global step index 0..191
    const int g_ = t & 15, jt_ = jtb + (t >> 4), pp = t & 1;
    const char* ga = (const char*)g_AT + ((size_t)g_ * N + i0) * 128 + gOff;
    const char* gb = (const char*)g_BT + ((size_t)g_ * N + (size_t)jt_ * 128) * 128 + gOff;
    char* la = (char*)&SM[pp][0][0] + wOff;
    char* lb = (char*)&SM[pp][1][0] + wOff;
#pragma unroll
    for (int it = 0; it < 4; ++it) {
      gload16(ga + it * 1024, la + it * 1024);
      gload16(gb + it * 1024, lb + it * 1024);
    }
  };

  stage(0);                                 // prologue batch

  if (tid < 128) {
    iaS[tid] = g_invA[i0 + tid];
    Top2 z; z.v0 = -1e30f; z.v1 = -1e30f; z.i0 = 0x7fffffff; z.i1 = 0x7fffffff;
    rowW[0][tid] = z; rowW[1][tid] = z;
  }
  __syncthreads();                          // drains batch 0 (once) + init visible

  // loop-invariant LDS fragment byte offsets (logical chunk ^ (row&7))
  const int f7 = fr & 7;
  const int cHi = (kq ^ f7) << 4;
  const int cLo = ((kq + 4) ^ f7) << 4;
  int aOff[4], bOff[4];
#pragma unroll
  for (int mi = 0; mi < 4; ++mi) aOff[mi] = (wr * 64 + mi * 16 + fr) * 128;
#pragma unroll
  for (int ni = 0; ni < 4; ++ni) bOff[ni] = (wc * 64 + ni * 16 + fr) * 128;

  int t = 0;
  for (int jt = jtb; jt < jtb + JT_PER_S; ++jt) {
    const int j0 = jt * 128;
    if (tid < 128) ibS[tid] = g_invB[j0 + tid];

    f32x4 acc[4][4];
#pragma unroll
    for (int mi = 0; mi < 4; ++mi)
#pragma unroll
      for (int ni = 0; ni < 4; ++ni)
#pragma unroll
        for (int q = 0; q < 4; ++q) acc[mi][ni][q] = 0.f;

    for (int g = 0; g < 16; ++g, ++t) {
      const int p = t & 1;
      __builtin_amdgcn_s_barrier();         // B1: buf[p^1] free to overwrite
      if (t + 1 < NSTEP) {
        stage(t + 1);                       // next batch rides through B2+MFMA
        asm volatile("s_waitcnt vmcnt(8)" ::: "memory");  // batch t landed
      } else {
        asm volatile("s_waitcnt vmcnt(0)" ::: "memory");  // final batch
      }
      __builtin_amdgcn_s_barrier();         // B2: everyone's batch t landed
      __builtin_amdgcn_sched_barrier(0);    // pin ds_reads below B2 (rule #18)

      const char* bA = (const char*)&SM[p][0][0];
      const char* bB = (const char*)&SM[p][1][0];
      f16x8 ah[4], al[4];
#pragma unroll
      for (int mi = 0; mi < 4; ++mi) {
        ah[mi] = *reinterpret_cast<const f16x8*>(bA + aOff[mi] + cHi);
        al[mi] = *reinterpret_cast<const f16x8*>(bA + aOff[mi] + cLo);
      }
#pragma unroll
      for (int ni = 0; ni < 4; ++ni) {
        f16x8 bh = *reinterpret_cast<const f16x8*>(bB + bOff[ni] + cHi);
        f16x8 bl = *reinterpret_cast<const f16x8*>(bB + bOff[ni] + cLo);
#pragma unroll
        for (int mi = 0; mi < 4; ++mi) {
          acc[mi][ni] = __builtin_amdgcn_mfma_f32_16x16x32_f16(ah[mi], bh, acc[mi][ni], 0, 0, 0);
          acc[mi][ni] = __builtin_amdgcn_mfma_f32_16x16x32_f16(ah[mi], bl, acc[mi][ni], 0, 0, 0);
          acc[mi][ni] = __builtin_amdgcn_mfma_f32_16x16x32_f16(al[mi], bh, acc[mi][ni], 0, 0, 0);
        }
      }
      asm volatile("" ::: "memory");
    }

    // ---- epilogue: scale to cosine sims (C layout: col=fr, row=kq*4+r) ----
    // (next j-tile's g=0 batch is in flight; it lands under these ~5k cycles)
    float ib[4];
#pragma unroll
    for (int ni = 0; ni < 4; ++ni) ib[ni] = ibS[wc * 64 + ni * 16 + fr];
#pragma unroll
    for (int mi = 0; mi < 4; ++mi)
#pragma unroll
      for (int r = 0; r < 4; ++r) {
        const float iar = iaS[wr * 64 + mi * 16 + kq * 4 + r];
#pragma unroll
        for (int ni = 0; ni < 4; ++ni)
          acc[mi][ni][r] *= iar * ib[ni];
      }

    // ---- row top-2 (reduce over cols: lanes sharing kq, then ni) ----
#pragma unroll
    for (int mi = 0; mi < 4; ++mi) {
#pragma unroll
      for (int r = 0; r < 4; ++r) {
        const int row = wr * 64 + mi * 16 + kq * 4 + r;
        float v0 = -1e30f, v1 = -1e30f; int id0 = 0x7fffffff, id1 = 0x7fffffff;
#pragma unroll
        for (int ni = 0; ni < 4; ++ni)
          t2_ins(acc[mi][ni][r], j0 + wc * 64 + ni * 16 + fr, v0, id0, v1, id1);
#pragma unroll
        for (int m = 1; m < 16; m <<= 1) {
          float ov0 = __shfl_xor(v0, m), ov1 = __shfl_xor(v1, m);
          int oi0 = __shfl_xor(id0, m), oi1 = __shfl_xor(id1, m);
          t2_ins(ov0, oi0, v0, id0, v1, id1);
          t2_ins(ov1, oi1, v0, id0, v1, id1);
        }
        if (fr == 0) {                     // unique (wave, kq, mi, r) owner
          Top2 tT = rowW[wc][row];
          t2_ins(v0, id0, tT.v0, tT.i0, tT.v1, tT.i1);
          t2_ins(v1, id1, tT.v0, tT.i0, tT.v1, tT.i1);
          rowW[wc][row] = tT;
        }
      }
    }

    // ---- col top-2 (reduce 16 in-thread rows, then across kq groups) ----
#pragma unroll
    for (int ni = 0; ni < 4; ++ni) {
      float v0 = -1e30f, v1 = -1e30f; int id0 = 0x7fffffff, id1 = 0x7fffffff;
#pragma unroll
      for (int mi = 0; mi < 4; ++mi)
#pragma unroll
        for (int r = 0; r < 4; ++r)
          t2_ins(acc[mi][ni][r], i0 + wr * 64 + mi * 16 + kq * 4 + r, v0, id0, v1, id1);
#pragma unroll
      for (int m = 16; m < 64; m <<= 1) {
        float ov0 = __shfl_xor(v0, m), ov1 = __shfl_xor(v1, m);
        int oi0 = __shfl_xor(id0, m), oi1 = __shfl_xor(id1, m);
        t2_ins(ov0, oi0, v0, id0, v1, id1);
        t2_ins(ov1, oi1, v0, id0, v1, id1);
      }
      if (kq == 0) {
        Top2 tT; tT.v0 = v0; tT.v1 = v1; tT.i0 = id0; tT.i1 = id1;
        colW[wr][wc * 64 + ni * 16 + fr] = tT;
      }
    }
    __syncthreads();                       // colW visible (also drains in-flight
                                           // batch -- it had the epilogue to land)
    if (tid < 128) {
      Top2 tT = colW[0][tid];
      Top2 o  = colW[1][tid];
      t2_ins(o.v0, o.i0, tT.v0, tT.i0, tT.v1, tT.i1);
      t2_ins(o.v1, o.i1, tT.v0, tT.i0, tT.v1, tT.i1);
      g_cpart[itile][j0 + tid] = tT;
    }
  }

  __syncthreads();
  if (tid < 128) {
    Top2 tT = rowW[0][tid];
    Top2 o  = rowW[1][tid];
    t2_ins(o.v0, o.i0, tT.v0, tT.i0, tT.v1, tT.i1);
    t2_ins(o.v1, o.i1, tT.v0, tT.i0, tT.v1, tT.i1);
    g_rpart[slice][i0 + tid] = tT;
  }
}

// ---------------- kernel 3: merge partials ----------------
__global__ void merge_kernel() {
  int i = blockIdx.x * 256 + threadIdx.x;
  if (i >= N) return;
  {
    float v0 = -1e30f, v1 = -1e30f; int id0 = 0x7fffffff, id1 = 0x7fffffff;
#pragma unroll
    for (int s = 0; s < NS; ++s) {
      Top2 p = g_rpart[s][i];
      t2_ins(p.v0, p.i0, v0, id0, v1, id1);
      t2_ins(p.v1, p.i1, v0, id0, v1, id1);
    }
    float d0 = 2.f - 2.f * v0, d1 = 2.f - 2.f * v1;
    g_nn12[i] = id0; g_r12[i] = d0 / (d1 + 1e-8f); g_sim0[i] = v0;
  }
  {
    float v0 = -1e30f, v1 = -1e30f; int id0 = 0x7fffffff, id1 = 0x7fffffff;
    for (int it = 0; it < NTILE; ++it) {
      Top2 p = g_cpart[it][i];
      t2_ins(p.v0, p.i0, v0, id0, v1, id1);
      t2_ins(p.v1, p.i1, v0, id0, v1, id1);
    }
    float d0 = 2.f - 2.f * v0, d1 = 2.f - 2.f * v1;
    g_nn21[i] = id0; g_r21[i] = d0 / (d1 + 1e-8f);
  }
}

// ---------------- kernel 4: mutual-NN + ratio mask, outputs ----------------
__global__ void finalize_kernel(float* __restrict__ out) {
  int i = blockIdx.x * 256 + threadIdx.x;
  if (i >= N) return;
  int j = g_nn12[i];
  int jc = j < 0 ? 0 : (j >= N ? N - 1 : j);
  bool mask = (g_nn21[jc] == i) && (g_r12[i] <= 0.95f) && (g_r21[jc] <= 0.95f);
  out[i]         = bf16_quant(mask ? g_sim0[i] : 0.f);
  out[N + i]     = bf16_quant((float)j);
  out[2 * N + i] = mask ? 1.f : 0.f;
}

extern "C" void kernel_launch(void* const* d_in, const int* in_sizes, int n_in,
                              void* d_out, int out_size, void* d_ws, size_t ws_size,
                              hipStream_t stream) {
  const float* A = (const float*)d_in[0];  // fp32, channel-major [CH][N]
  const float* B = (const float*)d_in[1];
  (void)d_ws; (void)ws_size;

  prep_kernel<<<dim3(192, 2), 256, 0, stream>>>(A, B);
  sim_top2_mfma<<<dim3(NTILE, NS), 256, 0, stream>>>();
  merge_kernel<<<dim3((N + 255) / 256), 256, 0, stream>>>();
  finalize_kernel<<<dim3((N + 255) / 256), 256, 0, stream>>>((float*)d_out);
}

// Round 7
// 3415.635 us; speedup vs baseline: 1.0507x; 1.0134x over previous
//
#include <hip/hip_runtime.h>
#include <stdint.h>

#define N      12288              // 96*128 descriptors
#define CH     512                // channels
#define NTILE  96                 // N/128
#define NS     8                  // j-slices (grid.y)
#define JT_PER_S 12               // j-tiles per slice
#define GPJ    8                  // K-steps per j-tile (BK = 64 channels)
#define NSTEP  (JT_PER_S * GPJ)   // 96 steps per block

typedef _Float16 f16x8 __attribute__((ext_vector_type(8)));
typedef float    f32x4 __attribute__((ext_vector_type(4)));

struct Top2 { float v0, v1; int i0, i1; };

// ---- module-scope device scratch (graph-capture safe, rewritten every launch)
__device__ float g_invA[N];
__device__ float g_invB[N];
// split-fp16 operands, K-MAJOR: [g32][d][8 chunks of 16B], g32 = 32-channel
// group. Within each 128B row ([32 hi | 32 lo] halfs) chunk c is stored at
// physical slot c^(d&7) -> a LINEAR copy into LDS yields bank-conflict-free
// ds_read_b128 fragment reads (verified: SQ_LDS_BANK_CONFLICT = 0, R4-R6).
__device__ unsigned short g_AT[(size_t)N * 1024];
__device__ unsigned short g_BT[(size_t)N * 1024];
__device__ Top2  g_rpart[NS][N];
__device__ Top2  g_cpart[NTILE][N];
__device__ int   g_nn12[N];
__device__ float g_r12[N];
__device__ float g_sim0[N];
__device__ int   g_nn21[N];
__device__ float g_r21[N];

// insert candidate (v, idx) into running top-2; ties -> lower index (lax.top_k)
__device__ __forceinline__ void t2_ins(float v, int idx,
                                       float& v0, int& i0, float& v1, int& i1) {
  bool beats0 = (v > v0) || (v == v0 && idx < i0);
  bool beats1 = (v > v1) || (v == v1 && idx < i1);
  if (beats0) { v1 = v0; i1 = i0; v0 = v; i0 = idx; }
  else if (beats1) { v1 = v; i1 = idx; }
}

__device__ __forceinline__ float bf16_quant(float f) {
  unsigned int u = __float_as_uint(f);
  unsigned int r = 0x7fffu + ((u >> 16) & 1u);
  unsigned int q = ((u + r) >> 16) << 16;
  return __uint_as_float(q);
}

// ---------------- kernel 1: transpose + split-fp16 + inverse norms ----------------
// grid (192, 2): 64 descriptors per block; y=0 -> A, y=1 -> B.
// x' = 1024*x (avoids fp16 subnormals); hi=fp16(x'), lo=fp16(x'-hi).
// Store K-MAJOR with per-row chunk swizzle c -> c^(d&7) (see g_AT comment).
__global__ __launch_bounds__(256)
void prep_kernel(const float* __restrict__ A, const float* __restrict__ B) {
  const int d0 = blockIdx.x * 64;
  const float* src = blockIdx.y ? B : A;
  unsigned short* dst = blockIdx.y ? g_BT : g_AT;
  float* inv = blockIdx.y ? g_invB : g_invA;

  __shared__ float Ls[32][68];            // fp32 in-tile (68: 16B-aligned rows)
  __shared__ unsigned short Os[64][64];   // packed out-tile [d][32 hi|32 lo]
  __shared__ float Ps[4][64];             // norm partials

  const int t = threadIdx.x;
  const int a = t >> 6, dl = t & 63;
  float sum = 0.f;

  for (int g = 0; g < 16; ++g) {
    __syncthreads();
    {   // load [32 ch][64 d] fp32 tile, coalesced
      const int c = t >> 3, dc = (t & 7) * 8;
      const float* p = src + (size_t)(g * 32 + c) * N + d0 + dc;
      float4 v0 = *reinterpret_cast<const float4*>(p);
      float4 v1 = *reinterpret_cast<const float4*>(p + 4);
      *reinterpret_cast<float4*>(&Ls[c][dc])     = v0;
      *reinterpret_cast<float4*>(&Ls[c][dc + 4]) = v1;
    }
    __syncthreads();
    {   // split 8 channels per thread, pack into Os
      _Float16 hv[8] __attribute__((aligned(16)));
      _Float16 lv[8] __attribute__((aligned(16)));
#pragma unroll
      for (int j = 0; j < 8; ++j) {
        float v = Ls[a * 8 + j][dl] * 1024.0f;
        sum += v * v;
        _Float16 h = (_Float16)v;
        float rr = v - (float)h;          // exact in fp32
        hv[j] = h;
        lv[j] = (_Float16)rr;
      }
      *reinterpret_cast<uint4*>(&Os[dl][a * 8])      = *reinterpret_cast<const uint4*>(hv);
      *reinterpret_cast<uint4*>(&Os[dl][32 + a * 8]) = *reinterpret_cast<const uint4*>(lv);
    }
    __syncthreads();
    {   // store out-tile K-major: row d of group g at ((g*N)+d0+d)*128 bytes
#pragma unroll
      for (int p2 = 0; p2 < 2; ++p2) {
        const int d = p2 * 32 + (t >> 3), ch = t & 7;
        const int sc = ch ^ (d & 7);      // swizzled chunk slot
        *reinterpret_cast<uint4*>((char*)dst
            + ((size_t)g * N + d0 + d) * 128 + sc * 16)
            = *reinterpret_cast<const uint4*>(&Os[d][ch * 8]);
      }
    }
  }
  Ps[a][dl] = sum;
  __syncthreads();
  if (t < 64) {
    float tot = Ps[0][t] + Ps[1][t] + Ps[2][t] + Ps[3][t];
    inv[d0 + t] = 1.0f / sqrtf(tot);
  }
}

// ---------------- kernel 2: MFMA GEMM + fused dual top-2 ----------------
// grid (96, 8), 512 threads / 8 waves. 128x128 tile; wave (wr=w&3, wc=w>>2)
// owns a 32x64 quadrant = 2x4 16x16 frags. BK=64 channels per step (2 MFMA
// k-chunks), 96 steps. REG-STAGED pipeline (T14): batch t+1's plain global
// loads are issued right after batch t's ds_write and stay in flight across
// the barrier + full compute phase (R1 proved reg-staging sustains this rate;
// global_load_lds at 8/wave/step was the R4-R6 stall). No inline asm.
// ~115 VGPR under __launch_bounds__(512,4) cap 128 -> no spill (R2 lesson);
// LDS 77 KB -> 2 blocks/CU = 16 waves/CU.
__global__ __launch_bounds__(512, 4)
void sim_top2_mfma() {
  __shared__ unsigned short SM[2][2][128 * 64]; // [kk][A/B][128 rows x 128B] = 64 KB
  __shared__ Top2 rowW[2][128];            // per-wc row partials (persistent)
  __shared__ Top2 colW[4][128];            // per-wr col partials (per j-tile)
  __shared__ float iaS[128];
  __shared__ float ibS[128];

  const int itile = blockIdx.x, slice = blockIdx.y;
  const int i0 = itile * 128;
  const int tid = threadIdx.x;
  const int wave = tid >> 6, lane = tid & 63;
  const int wr = wave & 3, wc = wave >> 2;
  const int fr = lane & 15, kq = lane >> 4;
  const int jtb = slice * JT_PER_S;

  // staging role: waves 0-3 (wc=0) stage A, waves 4-7 stage B. 128B/thread.
  const int tid2 = tid & 255;
  const char* opBase = (const char*)(wc ? g_BT : g_AT);
  const size_t strideG = (size_t)N * 128;   // bytes per 32-ch group stripe

  uint4 stage[8];
  auto issue = [&](int t) {                 // load batch t into regs
    const int gg = 2 * (t & 7);
    const size_t rb = wc ? (size_t)(jtb + (t >> 3)) * 128 : (size_t)i0;
    const char* base = opBase + ((size_t)gg * N + rb) * 128 + tid2 * 16;
#pragma unroll
    for (int n = 0; n < 8; ++n)
      stage[n] = *reinterpret_cast<const uint4*>(
          base + (size_t)(n >> 2) * strideG + (n & 3) * 4096);
  };

  issue(0);                                 // prologue batch, rides under init

  if (tid < 128) {
    iaS[tid] = g_invA[i0 + tid];
    Top2 z; z.v0 = -1e30f; z.v1 = -1e30f; z.i0 = 0x7fffffff; z.i1 = 0x7fffffff;
    rowW[0][tid] = z; rowW[1][tid] = z;
  }

  // loop-invariant LDS fragment byte offsets (logical chunk ^ (row&7))
  const int f7 = fr & 7;
  const int cHi = (kq ^ f7) << 4;
  const int cLo = ((kq + 4) ^ f7) << 4;
  int aOff[2], bOff[4];
#pragma unroll
  for (int mi = 0; mi < 2; ++mi) aOff[mi] = (wr * 32 + mi * 16 + fr) * 128;
#pragma unroll
  for (int ni = 0; ni < 4; ++ni) bOff[ni] = (wc * 64 + ni * 16 + fr) * 128;

  char* const SMb = (char*)&SM[0][0][0];
  char* const wbase = SMb + wc * 16384 + tid2 * 16;   // ds_write base

  int t = 0;
  for (int jt = jtb; jt < jtb + JT_PER_S; ++jt) {
    const int j0 = jt * 128;
    if (tid < 128) ibS[tid] = g_invB[j0 + tid];

    f32x4 acc[2][4];
#pragma unroll
    for (int mi = 0; mi < 2; ++mi)
#pragma unroll
      for (int ni = 0; ni < 4; ++ni)
#pragma unroll
        for (int q = 0; q < 4; ++q) acc[mi][ni][q] = 0.f;

    for (int g = 0; g < GPJ; ++g, ++t) {
      __syncthreads();                      // B1: buffer consumed by all waves
      // write batch t (compiler inserts the vmcnt wait for stage[] here;
      // at this point batch t is the ONLY outstanding set -> waits exactly it)
#pragma unroll
      for (int n = 0; n < 8; ++n)
        *reinterpret_cast<uint4*>(wbase + (n >> 2) * 32768 + (n & 3) * 4096)
            = stage[n];
      if (t + 1 < NSTEP) issue(t + 1);      // batch t+1 flies across B2+compute
      __syncthreads();                      // B2: tile t visible

#pragma unroll
      for (int kk = 0; kk < 2; ++kk) {
        const char* bA = SMb + kk * 32768;
        const char* bB = bA + 16384;
        f16x8 ah[2], al[2];
#pragma unroll
        for (int mi = 0; mi < 2; ++mi) {
          ah[mi] = *reinterpret_cast<const f16x8*>(bA + aOff[mi] + cHi);
          al[mi] = *reinterpret_cast<const f16x8*>(bA + aOff[mi] + cLo);
        }
#pragma unroll
        for (int ni = 0; ni < 4; ++ni) {
          f16x8 bh = *reinterpret_cast<const f16x8*>(bB + bOff[ni] + cHi);
          f16x8 bl = *reinterpret_cast<const f16x8*>(bB + bOff[ni] + cLo);
#pragma unroll
          for (int mi = 0; mi < 2; ++mi) {
            acc[mi][ni] = __builtin_amdgcn_mfma_f32_16x16x32_f16(ah[mi], bh, acc[mi][ni], 0, 0, 0);
            acc[mi][ni] = __builtin_amdgcn_mfma_f32_16x16x32_f16(ah[mi], bl, acc[mi][ni], 0, 0, 0);
            acc[mi][ni] = __builtin_amdgcn_mfma_f32_16x16x32_f16(al[mi], bh, acc[mi][ni], 0, 0, 0);
          }
        }
      }
    }

    // ---- epilogue: scale to cosine sims (C layout: col=fr, row=kq*4+r) ----
    // (next j-tile's batch is in flight; it lands under these cycles)
    float ib[4];
#pragma unroll
    for (int ni = 0; ni < 4; ++ni) ib[ni] = ibS[wc * 64 + ni * 16 + fr];
#pragma unroll
    for (int mi = 0; mi < 2; ++mi)
#pragma unroll
      for (int r = 0; r < 4; ++r) {
        const float iar = iaS[wr * 32 + mi * 16 + kq * 4 + r];
#pragma unroll
        for (int ni = 0; ni < 4; ++ni)
          acc[mi][ni][r] *= iar * ib[ni];
      }

    // ---- row top-2 (reduce over cols: 4 ni in-thread, then 16 fr lanes) ----
#pragma unroll
    for (int mi = 0; mi < 2; ++mi) {
#pragma unroll
      for (int r = 0; r < 4; ++r) {
        const int row = wr * 32 + mi * 16 + kq * 4 + r;
        float v0 = -1e30f, v1 = -1e30f; int id0 = 0x7fffffff, id1 = 0x7fffffff;
#pragma unroll
        for (int ni = 0; ni < 4; ++ni)
          t2_ins(acc[mi][ni][r], j0 + wc * 64 + ni * 16 + fr, v0, id0, v1, id1);
#pragma unroll
        for (int m = 1; m < 16; m <<= 1) {
          float ov0 = __shfl_xor(v0, m), ov1 = __shfl_xor(v1, m);
          int oi0 = __shfl_xor(id0, m), oi1 = __shfl_xor(id1, m);
          t2_ins(ov0, oi0, v0, id0, v1, id1);
          t2_ins(ov1, oi1, v0, id0, v1, id1);
        }
        if (fr == 0) {                      // unique (wave, kq, mi, r) owner
          Top2 tT = rowW[wc][row];
          t2_ins(v0, id0, tT.v0, tT.i0, tT.v1, tT.i1);
          t2_ins(v1, id1, tT.v0, tT.i0, tT.v1, tT.i1);
          rowW[wc][row] = tT;
        }
      }
    }

    // ---- col top-2 (reduce 8 in-thread rows, then across kq groups) ----
#pragma unroll
    for (int ni = 0; ni < 4; ++ni) {
      float v0 = -1e30f, v1 = -1e30f; int id0 = 0x7fffffff, id1 = 0x7fffffff;
#pragma unroll
      for (int mi = 0; mi < 2; ++mi)
#pragma unroll
        for (int r = 0; r < 4; ++r)
          t2_ins(acc[mi][ni][r], i0 + wr * 32 + mi * 16 + kq * 4 + r, v0, id0, v1, id1);
#pragma unroll
      for (int m = 16; m < 64; m <<= 1) {
        float ov0 = __shfl_xor(v0, m), ov1 = __shfl_xor(v1, m);
        int oi0 = __shfl_xor(id0, m), oi1 = __shfl_xor(id1, m);
        t2_ins(ov0, oi0, v0, id0, v1, id1);
        t2_ins(ov1, oi1, v0, id0, v1, id1);
      }
      if (kq == 0) {
        Top2 tT; tT.v0 = v0; tT.v1 = v1; tT.i0 = id0; tT.i1 = id1;
        colW[wr][wc * 64 + ni * 16 + fr] = tT;
      }
    }
    __syncthreads();
    if (tid < 128) {
      Top2 tT = colW[0][tid];
#pragma unroll
      for (int w = 1; w < 4; ++w) {
        Top2 o = colW[w][tid];
        t2_ins(o.v0, o.i0, tT.v0, tT.i0, tT.v1, tT.i1);
        t2_ins(o.v1, o.i1, tT.v0, tT.i0, tT.v1, tT.i1);
      }
      g_cpart[itile][j0 + tid] = tT;
    }
  }

  __syncthreads();
  if (tid < 128) {
    Top2 tT = rowW[0][tid];
    Top2 o  = rowW[1][tid];
    t2_ins(o.v0, o.i0, tT.v0, tT.i0, tT.v1, tT.i1);
    t2_ins(o.v1, o.i1, tT.v0, tT.i0, tT.v1, tT.i1);
    g_rpart[slice][i0 + tid] = tT;
  }
}

// ---------------- kernel 3: merge partials ----------------
__global__ void merge_kernel() {
  int i = blockIdx.x * 256 + threadIdx.x;
  if (i >= N) return;
  {
    float v0 = -1e30f, v1 = -1e30f; int id0 = 0x7fffffff, id1 = 0x7fffffff;
#pragma unroll
    for (int s = 0; s < NS; ++s) {
      Top2 p = g_rpart[s][i];
      t2_ins(p.v0, p.i0, v0, id0, v1, id1);
      t2_ins(p.v1, p.i1, v0, id0, v1, id1);
    }
    float d0 = 2.f - 2.f * v0, d1 = 2.f - 2.f * v1;
    g_nn12[i] = id0; g_r12[i] = d0 / (d1 + 1e-8f); g_sim0[i] = v0;
  }
  {
    float v0 = -1e30f, v1 = -1e30f; int id0 = 0x7fffffff, id1 = 0x7fffffff;
    for (int it = 0; it < NTILE; ++it) {
      Top2 p = g_cpart[it][i];
      t2_ins(p.v0, p.i0, v0, id0, v1, id1);
      t2_ins(p.v1, p.i1, v0, id0, v1, id1);
    }
    float d0 = 2.f - 2.f * v0, d1 = 2.f - 2.f * v1;
    g_nn21[i] = id0; g_r21[i] = d0 / (d1 + 1e-8f);
  }
}

// ---------------- kernel 4: mutual-NN + ratio mask, outputs ----------------
__global__ void finalize_kernel(float* __restrict__ out) {
  int i = blockIdx.x * 256 + threadIdx.x;
  if (i >= N) return;
  int j = g_nn12[i];
  int jc = j < 0 ? 0 : (j >= N ? N - 1 : j);
  bool mask = (g_nn21[jc] == i) && (g_r12[i] <= 0.95f) && (g_r21[jc] <= 0.95f);
  out[i]         = bf16_quant(mask ? g_sim0[i] : 0.f);
  out[N + i]     = bf16_quant((float)j);
  out[2 * N + i] = mask ? 1.f : 0.f;
}

extern "C" void kernel_launch(void* const* d_in, const int* in_sizes, int n_in,
                              void* d_out, int out_size, void* d_ws, size_t ws_size,
                              hipStream_t stream) {
  const float* A = (const float*)d_in[0];  // fp32, channel-major [CH][N]
  const float* B = (const float*)d_in[1];
  (void)d_ws; (void)ws_size;

  prep_kernel<<<dim3(192, 2), 256, 0, stream>>>(A, B);
  sim_top2_mfma<<<dim3(NTILE, NS), 512, 0, stream>>>();
  merge_kernel<<<dim3((N + 255) / 256), 256, 0, stream>>>();
  finalize_kernel<<<dim3((N + 255) / 256), 256, 0, stream>>>((float*)d_out);
}

// Round 8
// 2449.469 us; speedup vs baseline: 1.4651x; 1.3944x over previous
//
#include <hip/hip_runtime.h>
#include <stdint.h>

#define N      12288              // 96*128 descriptors
#define CH     512                // channels
#define NTILE  96                 // N/128
#define NS     8                  // j-slices (grid.y)
#define JT_PER_S 12               // j-tiles per slice
#define GPJ    16                 // K-steps per j-tile (BK = 32 channels)
#define NSTEP  (JT_PER_S * GPJ)   // 192 steps per block

typedef _Float16 f16x8 __attribute__((ext_vector_type(8)));
typedef float    f32x4 __attribute__((ext_vector_type(4)));

struct Top2 { float v0, v1; int i0, i1; };

// ---- module-scope device scratch (graph-capture safe, rewritten every launch)
__device__ float g_invA[N];
__device__ float g_invB[N];
// split-fp16 operands, K-MAJOR: [g32][d][8 chunks of 16B], g32 = 32-channel
// group. Within each 128B row ([32 hi | 32 lo] halfs) chunk c is stored at
// physical slot c^(d&7) -> LINEAR copy into LDS yields bank-conflict-free
// ds_read_b128 fragment reads (verified: SQ_LDS_BANK_CONFLICT = 0, R4-R7).
__device__ unsigned short g_AT[(size_t)N * 1024];
__device__ unsigned short g_BT[(size_t)N * 1024];
__device__ Top2  g_rpart[NS][N];
__device__ Top2  g_cpart[NTILE][N];
__device__ int   g_nn12[N];
__device__ float g_r12[N];
__device__ float g_sim0[N];
__device__ int   g_nn21[N];
__device__ float g_r21[N];

// insert candidate (v, idx) into running top-2; ties -> lower index (lax.top_k)
__device__ __forceinline__ void t2_ins(float v, int idx,
                                       float& v0, int& i0, float& v1, int& i1) {
  bool beats0 = (v > v0) || (v == v0 && idx < i0);
  bool beats1 = (v > v1) || (v == v1 && idx < i1);
  if (beats0) { v1 = v0; i1 = i0; v0 = v; i0 = idx; }
  else if (beats1) { v1 = v; i1 = idx; }
}

__device__ __forceinline__ float bf16_quant(float f) {
  unsigned int u = __float_as_uint(f);
  unsigned int r = 0x7fffu + ((u >> 16) & 1u);
  unsigned int q = ((u + r) >> 16) << 16;
  return __uint_as_float(q);
}

// ---------------- kernel 1: transpose + split-fp16 + inverse norms ----------------
// grid (192, 2): 64 descriptors per block; y=0 -> A, y=1 -> B.
// x' = 1024*x (avoids fp16 subnormals); hi=fp16(x'), lo=fp16(x'-hi).
// Store K-MAJOR with per-row chunk swizzle c -> c^(d&7) (see g_AT comment).
__global__ __launch_bounds__(256)
void prep_kernel(const float* __restrict__ A, const float* __restrict__ B) {
  const int d0 = blockIdx.x * 64;
  const float* src = blockIdx.y ? B : A;
  unsigned short* dst = blockIdx.y ? g_BT : g_AT;
  float* inv = blockIdx.y ? g_invB : g_invA;

  __shared__ float Ls[32][68];            // fp32 in-tile (68: 16B-aligned rows)
  __shared__ unsigned short Os[64][64];   // packed out-tile [d][32 hi|32 lo]
  __shared__ float Ps[4][64];             // norm partials

  const int t = threadIdx.x;
  const int a = t >> 6, dl = t & 63;
  float sum = 0.f;

  for (int g = 0; g < 16; ++g) {
    __syncthreads();
    {   // load [32 ch][64 d] fp32 tile, coalesced
      const int c = t >> 3, dc = (t & 7) * 8;
      const float* p = src + (size_t)(g * 32 + c) * N + d0 + dc;
      float4 v0 = *reinterpret_cast<const float4*>(p);
      float4 v1 = *reinterpret_cast<const float4*>(p + 4);
      *reinterpret_cast<float4*>(&Ls[c][dc])     = v0;
      *reinterpret_cast<float4*>(&Ls[c][dc + 4]) = v1;
    }
    __syncthreads();
    {   // split 8 channels per thread, pack into Os
      _Float16 hv[8] __attribute__((aligned(16)));
      _Float16 lv[8] __attribute__((aligned(16)));
#pragma unroll
      for (int j = 0; j < 8; ++j) {
        float v = Ls[a * 8 + j][dl] * 1024.0f;
        sum += v * v;
        _Float16 h = (_Float16)v;
        float rr = v - (float)h;          // exact in fp32
        hv[j] = h;
        lv[j] = (_Float16)rr;
      }
      *reinterpret_cast<uint4*>(&Os[dl][a * 8])      = *reinterpret_cast<const uint4*>(hv);
      *reinterpret_cast<uint4*>(&Os[dl][32 + a * 8]) = *reinterpret_cast<const uint4*>(lv);
    }
    __syncthreads();
    {   // store out-tile K-major: row d of group g at ((g*N)+d0+d)*128 bytes
#pragma unroll
      for (int p2 = 0; p2 < 2; ++p2) {
        const int d = p2 * 32 + (t >> 3), ch = t & 7;
        const int sc = ch ^ (d & 7);      // swizzled chunk slot
        *reinterpret_cast<uint4*>((char*)dst
            + ((size_t)g * N + d0 + d) * 128 + sc * 16)
            = *reinterpret_cast<const uint4*>(&Os[d][ch * 8]);
      }
    }
  }
  Ps[a][dl] = sum;
  __syncthreads();
  if (t < 64) {
    float tot = Ps[0][t] + Ps[1][t] + Ps[2][t] + Ps[3][t];
    inv[d0 + t] = 1.0f / sqrtf(tot);
  }
}

// ---------------- kernel 2: MFMA GEMM + fused dual top-2 ----------------
// grid (96, 8), 512 threads / 8 waves. 128x128 tile; wave (wr=w&3, wc=w>>2)
// owns a 32x64 quadrant = 2x4 16x16 frags. BK=32 per step, 192 steps.
// REG-STAGED double-buffered pipeline: batch t+1 (4 NAMED uint4 per thread,
// 64 B) is issued right after batch t's ds_write and stays in flight across
// the barrier + compute.  R7's stage[8] (128 B/thread) blew the (512,4)
// 128-reg cap -> compiler put it in SCRATCH (WRITE_SIZE 4.7 GB = exactly the
// staged bytes).  BK=32 halves the footprint: ~90 live regs, no spill.
__global__ __launch_bounds__(512, 4)
void sim_top2_mfma() {
  __shared__ unsigned short SM[2][2][128 * 64]; // [parity][A/B][128 x 128B] = 64 KB
  __shared__ Top2 rowW[2][128];            // per-wc row partials (persistent)
  __shared__ Top2 colW[4][128];            // per-wr col partials (per j-tile)
  __shared__ float iaS[128];
  __shared__ float ibS[128];

  const int itile = blockIdx.x, slice = blockIdx.y;
  const int i0 = itile * 128;
  const int tid = threadIdx.x;
  const int wave = tid >> 6, lane = tid & 63;
  const int wr = wave & 3, wc = wave >> 2;
  const int fr = lane & 15, kq = lane >> 4;
  const int jtb = slice * JT_PER_S;

  // staging role: waves 0-3 (wc=0) stage A, waves 4-7 stage B. 64 B/thread,
  // chunk n at byte n*4096 + tid2*16 -> stride-16 b128 = conflict-free.
  const int tid2 = tid & 255;
  const char* opBase = (const char*)(wc ? g_BT : g_AT);

  uint4 s0, s1, s2, s3;                    // NAMED staging regs (rule #20)
  auto issue = [&](int t) {                // load batch t into regs
    const int gg = t & 15;
    const size_t rb = wc ? (size_t)(jtb + (t >> 4)) * 128 : (size_t)i0;
    const char* base = opBase + ((size_t)gg * N + rb) * 128 + tid2 * 16;
    s0 = *reinterpret_cast<const uint4*>(base);
    s1 = *reinterpret_cast<const uint4*>(base + 4096);
    s2 = *reinterpret_cast<const uint4*>(base + 8192);
    s3 = *reinterpret_cast<const uint4*>(base + 12288);
  };

  issue(0);                                 // prologue batch, rides under init

  if (tid < 128) {
    iaS[tid] = g_invA[i0 + tid];
    Top2 z; z.v0 = -1e30f; z.v1 = -1e30f; z.i0 = 0x7fffffff; z.i1 = 0x7fffffff;
    rowW[0][tid] = z; rowW[1][tid] = z;
  }

  // loop-invariant LDS fragment byte offsets (logical chunk ^ (row&7))
  const int f7 = fr & 7;
  const int cHi = (kq ^ f7) << 4;
  const int cLo = ((kq + 4) ^ f7) << 4;
  int aOff[2], bOff[4];
#pragma unroll
  for (int mi = 0; mi < 2; ++mi) aOff[mi] = (wr * 32 + mi * 16 + fr) * 128;
#pragma unroll
  for (int ni = 0; ni < 4; ++ni) bOff[ni] = (wc * 64 + ni * 16 + fr) * 128;

  char* const SMb = (char*)&SM[0][0][0];
  char* const wbase0 = SMb + wc * 16384 + tid2 * 16;  // + parity*32768

  int t = 0;
  for (int jt = jtb; jt < jtb + JT_PER_S; ++jt) {
    const int j0 = jt * 128;
    if (tid < 128) ibS[tid] = g_invB[j0 + tid];

    f32x4 acc[2][4];
#pragma unroll
    for (int mi = 0; mi < 2; ++mi)
#pragma unroll
      for (int ni = 0; ni < 4; ++ni)
#pragma unroll
        for (int q = 0; q < 4; ++q) acc[mi][ni][q] = 0.f;

    for (int g = 0; g < GPJ; ++g, ++t) {
      const int par = t & 1;
      __syncthreads();                      // B1: buf[par] consumed by all waves
      {                                     // write batch t (compiler waits the
        char* wb = wbase0 + par * 32768;    //  stage regs' vmcnt right here)
        *reinterpret_cast<uint4*>(wb)          = s0;
        *reinterpret_cast<uint4*>(wb + 4096)   = s1;
        *reinterpret_cast<uint4*>(wb + 8192)   = s2;
        *reinterpret_cast<uint4*>(wb + 12288)  = s3;
      }
      if (t + 1 < NSTEP) issue(t + 1);      // batch t+1 flies across B2+compute
      __syncthreads();                      // B2: tile t visible

      const char* bA = SMb + par * 32768;
      const char* bB = bA + 16384;
      f16x8 ah[2], al[2];
#pragma unroll
      for (int mi = 0; mi < 2; ++mi) {
        ah[mi] = *reinterpret_cast<const f16x8*>(bA + aOff[mi] + cHi);
        al[mi] = *reinterpret_cast<const f16x8*>(bA + aOff[mi] + cLo);
      }
#pragma unroll
      for (int ni = 0; ni < 4; ++ni) {
        f16x8 bh = *reinterpret_cast<const f16x8*>(bB + bOff[ni] + cHi);
        f16x8 bl = *reinterpret_cast<const f16x8*>(bB + bOff[ni] + cLo);
#pragma unroll
        for (int mi = 0; mi < 2; ++mi) {
          acc[mi][ni] = __builtin_amdgcn_mfma_f32_16x16x32_f16(ah[mi], bh, acc[mi][ni], 0, 0, 0);
          acc[mi][ni] = __builtin_amdgcn_mfma_f32_16x16x32_f16(ah[mi], bl, acc[mi][ni], 0, 0, 0);
          acc[mi][ni] = __builtin_amdgcn_mfma_f32_16x16x32_f16(al[mi], bh, acc[mi][ni], 0, 0, 0);
        }
      }
    }

    // ---- epilogue: scale to cosine sims (C layout: col=fr, row=kq*4+r) ----
    // (next j-tile's batch is in flight; it lands under these cycles)
    float ib[4];
#pragma unroll
    for (int ni = 0; ni < 4; ++ni) ib[ni] = ibS[wc * 64 + ni * 16 + fr];
#pragma unroll
    for (int mi = 0; mi < 2; ++mi)
#pragma unroll
      for (int r = 0; r < 4; ++r) {
        const float iar = iaS[wr * 32 + mi * 16 + kq * 4 + r];
#pragma unroll
        for (int ni = 0; ni < 4; ++ni)
          acc[mi][ni][r] *= iar * ib[ni];
      }

    // ---- row top-2 (reduce over cols: 4 ni in-thread, then 16 fr lanes) ----
#pragma unroll
    for (int mi = 0; mi < 2; ++mi) {
#pragma unroll
      for (int r = 0; r < 4; ++r) {
        const int row = wr * 32 + mi * 16 + kq * 4 + r;
        float v0 = -1e30f, v1 = -1e30f; int id0 = 0x7fffffff, id1 = 0x7fffffff;
#pragma unroll
        for (int ni = 0; ni < 4; ++ni)
          t2_ins(acc[mi][ni][r], j0 + wc * 64 + ni * 16 + fr, v0, id0, v1, id1);
#pragma unroll
        for (int m = 1; m < 16; m <<= 1) {
          float ov0 = __shfl_xor(v0, m), ov1 = __shfl_xor(v1, m);
          int oi0 = __shfl_xor(id0, m), oi1 = __shfl_xor(id1, m);
          t2_ins(ov0, oi0, v0, id0, v1, id1);
          t2_ins(ov1, oi1, v0, id0, v1, id1);
        }
        if (fr == 0) {                      // unique (wave, kq, mi, r) owner
          Top2 tT = rowW[wc][row];
          t2_ins(v0, id0, tT.v0, tT.i0, tT.v1, tT.i1);
          t2_ins(v1, id1, tT.v0, tT.i0, tT.v1, tT.i1);
          rowW[wc][row] = tT;
        }
      }
    }

    // ---- col top-2 (reduce 8 in-thread rows, then across kq groups) ----
#pragma unroll
    for (int ni = 0; ni < 4; ++ni) {
      float v0 = -1e30f, v1 = -1e30f; int id0 = 0x7fffffff, id1 = 0x7fffffff;
#pragma unroll
      for (int mi = 0; mi < 2; ++mi)
#pragma unroll
        for (int r = 0; r < 4; ++r)
          t2_ins(acc[mi][ni][r], i0 + wr * 32 + mi * 16 + kq * 4 + r, v0, id0, v1, id1);
#pragma unroll
      for (int m = 16; m < 64; m <<= 1) {
        float ov0 = __shfl_xor(v0, m), ov1 = __shfl_xor(v1, m);
        int oi0 = __shfl_xor(id0, m), oi1 = __shfl_xor(id1, m);
        t2_ins(ov0, oi0, v0, id0, v1, id1);
        t2_ins(ov1, oi1, v0, id0, v1, id1);
      }
      if (kq == 0) {
        Top2 tT; tT.v0 = v0; tT.v1 = v1; tT.i0 = id0; tT.i1 = id1;
        colW[wr][wc * 64 + ni * 16 + fr] = tT;
      }
    }
    __syncthreads();
    if (tid < 128) {
      Top2 tT = colW[0][tid];
#pragma unroll
      for (int w = 1; w < 4; ++w) {
        Top2 o = colW[w][tid];
        t2_ins(o.v0, o.i0, tT.v0, tT.i0, tT.v1, tT.i1);
        t2_ins(o.v1, o.i1, tT.v0, tT.i0, tT.v1, tT.i1);
      }
      g_cpart[itile][j0 + tid] = tT;
    }
  }

  __syncthreads();
  if (tid < 128) {
    Top2 tT = rowW[0][tid];
    Top2 o  = rowW[1][tid];
    t2_ins(o.v0, o.i0, tT.v0, tT.i0, tT.v1, tT.i1);
    t2_ins(o.v1, o.i1, tT.v0, tT.i0, tT.v1, tT.i1);
    g_rpart[slice][i0 + tid] = tT;
  }
}

// ---------------- kernel 3: merge partials ----------------
__global__ void merge_kernel() {
  int i = blockIdx.x * 256 + threadIdx.x;
  if (i >= N) return;
  {
    float v0 = -1e30f, v1 = -1e30f; int id0 = 0x7fffffff, id1 = 0x7fffffff;
#pragma unroll
    for (int s = 0; s < NS; ++s) {
      Top2 p = g_rpart[s][i];
      t2_ins(p.v0, p.i0, v0, id0, v1, id1);
      t2_ins(p.v1, p.i1, v0, id0, v1, id1);
    }
    float d0 = 2.f - 2.f * v0, d1 = 2.f - 2.f * v1;
    g_nn12[i] = id0; g_r12[i] = d0 / (d1 + 1e-8f); g_sim0[i] = v0;
  }
  {
    float v0 = -1e30f, v1 = -1e30f; int id0 = 0x7fffffff, id1 = 0x7fffffff;
    for (int it = 0; it < NTILE; ++it) {
      Top2 p = g_cpart[it][i];
      t2_ins(p.v0, p.i0, v0, id0, v1, id1);
      t2_ins(p.v1, p.i1, v0, id0, v1, id1);
    }
    float d0 = 2.f - 2.f * v0, d1 = 2.f - 2.f * v1;
    g_nn21[i] = id0; g_r21[i] = d0 / (d1 + 1e-8f);
  }
}

// ---------------- kernel 4: mutual-NN + ratio mask, outputs ----------------
__global__ void finalize_kernel(float* __restrict__ out) {
  int i = blockIdx.x * 256 + threadIdx.x;
  if (i >= N) return;
  int j = g_nn12[i];
  int jc = j < 0 ? 0 : (j >= N ? N - 1 : j);
  bool mask = (g_nn21[jc] == i) && (g_r12[i] <= 0.95f) && (g_r21[jc] <= 0.95f);
  out[i]         = bf16_quant(mask ? g_sim0[i] : 0.f);
  out[N + i]     = bf16_quant((float)j);
  out[2 * N + i] = mask ? 1.f : 0.f;
}

extern "C" void kernel_launch(void* const* d_in, const int* in_sizes, int n_in,
                              void* d_out, int out_size, void* d_ws, size_t ws_size,
                              hipStream_t stream) {
  const float* A = (const float*)d_in[0];  // fp32, channel-major [CH][N]
  const float* B = (const float*)d_in[1];
  (void)d_ws; (void)ws_size;

  prep_kernel<<<dim3(192, 2), 256, 0, stream>>>(A, B);
  sim_top2_mfma<<<dim3(NTILE, NS), 512, 0, stream>>>();
  merge_kernel<<<dim3((N + 255) / 256), 256, 0, stream>>>();
  finalize_kernel<<<dim3((N + 255) / 256), 256, 0, stream>>>((float*)d_out);
}

// Round 9
// 2433.917 us; speedup vs baseline: 1.4745x; 1.0064x over previous
//
#include <hip/hip_runtime.h>
#include <stdint.h>

#define N      12288              // 96*128 descriptors
#define CH     512                // channels
#define NTILE  96                 // N/128
#define NS     8                  // j-slices
#define JT_PER_S 12               // j-tiles per slice
#define GPJ    16                 // K-steps per j-tile (BK = 32 channels)
#define NSTEP  (JT_PER_S * GPJ)   // 192 steps per block

typedef _Float16 f16x8 __attribute__((ext_vector_type(8)));
typedef float    f32x4 __attribute__((ext_vector_type(4)));

struct Top2 { float v0, v1; int i0, i1; };

// ---- module-scope device scratch (graph-capture safe, rewritten every launch)
__device__ float g_invA[N];
__device__ float g_invB[N];
// split-fp16 operands, K-MAJOR: [g32][d][8 chunks of 16B], g32 = 32-channel
// group. Within each 128B row ([32 hi | 32 lo] halfs) chunk c is stored at
// physical slot c^(d&7) -> LINEAR copy into LDS yields bank-conflict-free
// ds_read_b128 fragment reads (verified: SQ_LDS_BANK_CONFLICT = 0, R4-R8).
__device__ unsigned short g_AT[(size_t)N * 1024];
__device__ unsigned short g_BT[(size_t)N * 1024];
__device__ Top2  g_rpart[NS][N];
__device__ Top2  g_cpart[NTILE][N];
__device__ int   g_nn12[N];
__device__ float g_r12[N];
__device__ float g_sim0[N];
__device__ int   g_nn21[N];
__device__ float g_r21[N];

// insert candidate (v, idx) into running top-2; ties -> lower index (lax.top_k)
__device__ __forceinline__ void t2_ins(float v, int idx,
                                       float& v0, int& i0, float& v1, int& i1) {
  bool beats0 = (v > v0) || (v == v0 && idx < i0);
  bool beats1 = (v > v1) || (v == v1 && idx < i1);
  if (beats0) { v1 = v0; i1 = i0; v0 = v; i0 = idx; }
  else if (beats1) { v1 = v; i1 = idx; }
}

__device__ __forceinline__ float bf16_quant(float f) {
  unsigned int u = __float_as_uint(f);
  unsigned int r = 0x7fffu + ((u >> 16) & 1u);
  unsigned int q = ((u + r) >> 16) << 16;
  return __uint_as_float(q);
}

// ---------------- kernel 1: transpose + split-fp16 + inverse norms ----------------
__global__ __launch_bounds__(256)
void prep_kernel(const float* __restrict__ A, const float* __restrict__ B) {
  const int d0 = blockIdx.x * 64;
  const float* src = blockIdx.y ? B : A;
  unsigned short* dst = blockIdx.y ? g_BT : g_AT;
  float* inv = blockIdx.y ? g_invB : g_invA;

  __shared__ float Ls[32][68];            // fp32 in-tile (68: 16B-aligned rows)
  __shared__ unsigned short Os[64][64];   // packed out-tile [d][32 hi|32 lo]
  __shared__ float Ps[4][64];             // norm partials

  const int t = threadIdx.x;
  const int a = t >> 6, dl = t & 63;
  float sum = 0.f;

  for (int g = 0; g < 16; ++g) {
    __syncthreads();
    {   // load [32 ch][64 d] fp32 tile, coalesced
      const int c = t >> 3, dc = (t & 7) * 8;
      const float* p = src + (size_t)(g * 32 + c) * N + d0 + dc;
      float4 v0 = *reinterpret_cast<const float4*>(p);
      float4 v1 = *reinterpret_cast<const float4*>(p + 4);
      *reinterpret_cast<float4*>(&Ls[c][dc])     = v0;
      *reinterpret_cast<float4*>(&Ls[c][dc + 4]) = v1;
    }
    __syncthreads();
    {   // split 8 channels per thread, pack into Os
      _Float16 hv[8] __attribute__((aligned(16)));
      _Float16 lv[8] __attribute__((aligned(16)));
#pragma unroll
      for (int j = 0; j < 8; ++j) {
        float v = Ls[a * 8 + j][dl] * 1024.0f;
        sum += v * v;
        _Float16 h = (_Float16)v;
        float rr = v - (float)h;          // exact in fp32
        hv[j] = h;
        lv[j] = (_Float16)rr;
      }
      *reinterpret_cast<uint4*>(&Os[dl][a * 8])      = *reinterpret_cast<const uint4*>(hv);
      *reinterpret_cast<uint4*>(&Os[dl][32 + a * 8]) = *reinterpret_cast<const uint4*>(lv);
    }
    __syncthreads();
    {   // store out-tile K-major: row d of group g, chunks XOR-swizzled
#pragma unroll
      for (int p2 = 0; p2 < 2; ++p2) {
        const int d = p2 * 32 + (t >> 3), ch = t & 7;
        const int sc = ch ^ (d & 7);      // swizzled chunk slot
        *reinterpret_cast<uint4*>((char*)dst
            + ((size_t)g * N + d0 + d) * 128 + sc * 16)
            = *reinterpret_cast<const uint4*>(&Os[d][ch * 8]);
      }
    }
  }
  Ps[a][dl] = sum;
  __syncthreads();
  if (t < 64) {
    float tot = Ps[0][t] + Ps[1][t] + Ps[2][t] + Ps[3][t];
    inv[d0 + t] = 1.0f / sqrtf(tot);
  }
}

// ---------------- kernel 2: MFMA GEMM + fused dual top-2 ----------------
// grid (96,8) remapped XCD-local: bid=96s+8q+r -> itile=12r+q, slice=s, so
// XCD r hosts 12 contiguous itiles x all slices (A-footprint 3MB + in-phase
// B-footprint 2MB ~ fits 4MB L2; was ~30MB thrash, FETCH 12x over).
// 512 thr / 8 waves; wave (wr=w&3,wc=w>>2) owns 32x64 = 2x4 16x16 frags.
// DEPTH-2 reg pipeline with RAW barriers: R8's __syncthreads drained vmcnt
// at every barrier, nullifying prefetch. Here batch t+2 is issued at step t
// and only its own registers' vmcnt is awaited (compiler-counted) at step
// t+2's ds_write -> 2 full steps of cover, no vmcnt(0) in the K-loop.
__global__ __launch_bounds__(512, 4)
void sim_top2_mfma() {
  __shared__ unsigned short SM[2][2][128 * 64]; // [parity][A/B][128 x 128B] = 64 KB
  __shared__ Top2 rowW[2][128];            // per-wc row partials (persistent)
  __shared__ Top2 colW[4][128];            // per-wr col partials (per j-tile)
  __shared__ float iaS[128];
  __shared__ float ibS[128];

  const int bid = blockIdx.x + NTILE * blockIdx.y;        // linear dispatch id
  const int itile = (bid & 7) * 12 + ((bid >> 3) % 12);   // XCD-local remap
  const int slice = bid / NTILE;                          // bijective (see hdr)
  const int i0 = itile * 128;
  const int tid = threadIdx.x;
  const int wave = tid >> 6, lane = tid & 63;
  const int wr = wave & 3, wc = wave >> 2;
  const int fr = lane & 15, kq = lane >> 4;
  const int jtb = slice * JT_PER_S;

  // staging role: waves 0-3 (wc=0) stage A, waves 4-7 stage B. 64 B/thread,
  // chunk n at byte n*4096 + tid2*16 -> stride-16 b128 = conflict-free.
  const int tid2 = tid & 255;
  const char* opBase = (const char*)(wc ? g_BT : g_AT);

  uint4 sa0, sa1, sa2, sa3;                // batch set A (even steps)
  uint4 sb0, sb1, sb2, sb3;                // batch set B (odd steps)
  auto issueA = [&](int t) {
    const int gg = t & 15;
    const size_t rb = wc ? (size_t)(jtb + (t >> 4)) * 128 : (size_t)i0;
    const char* base = opBase + ((size_t)gg * N + rb) * 128 + tid2 * 16;
    sa0 = *reinterpret_cast<const uint4*>(base);
    sa1 = *reinterpret_cast<const uint4*>(base + 4096);
    sa2 = *reinterpret_cast<const uint4*>(base + 8192);
    sa3 = *reinterpret_cast<const uint4*>(base + 12288);
  };
  auto issueB = [&](int t) {
    const int gg = t & 15;
    const size_t rb = wc ? (size_t)(jtb + (t >> 4)) * 128 : (size_t)i0;
    const char* base = opBase + ((size_t)gg * N + rb) * 128 + tid2 * 16;
    sb0 = *reinterpret_cast<const uint4*>(base);
    sb1 = *reinterpret_cast<const uint4*>(base + 4096);
    sb2 = *reinterpret_cast<const uint4*>(base + 8192);
    sb3 = *reinterpret_cast<const uint4*>(base + 12288);
  };

  if (tid < 128) {
    iaS[tid] = g_invA[i0 + tid];
    Top2 z; z.v0 = -1e30f; z.v1 = -1e30f; z.i0 = 0x7fffffff; z.i1 = 0x7fffffff;
    rowW[0][tid] = z; rowW[1][tid] = z;
  }
  __syncthreads();                          // init visible

  issueA(0);                                // prologue: batches 0,1 in flight
  issueB(1);

  // loop-invariant LDS fragment byte offsets (logical chunk ^ (row&7))
  const int f7 = fr & 7;
  const int cHi = (kq ^ f7) << 4;
  const int cLo = ((kq + 4) ^ f7) << 4;
  int aOff[2], bOff[4];
#pragma unroll
  for (int mi = 0; mi < 2; ++mi) aOff[mi] = (wr * 32 + mi * 16 + fr) * 128;
#pragma unroll
  for (int ni = 0; ni < 4; ++ni) bOff[ni] = (wc * 64 + ni * 16 + fr) * 128;

  char* const SMb = (char*)&SM[0][0][0];
  char* const wbase0 = SMb + wc * 16384 + tid2 * 16;  // + parity*32768

// one K-step: raw barrier; ds_write batch t from the given reg set (compiler
// waits exactly that set's vmcnt); re-issue batch t+2 into the same set;
// lgkmcnt(0) (LDS only -- vmem stays in flight) ; raw barrier ; MFMA.
#define KSTEP(PAR, S0, S1, S2, S3, ISSUE, TT)                                 \
  {                                                                           \
    __builtin_amdgcn_s_barrier();                                             \
    asm volatile("" ::: "memory");                                            \
    {                                                                         \
      char* wb = wbase0 + (PAR) * 32768;                                      \
      *reinterpret_cast<uint4*>(wb)         = S0;                             \
      *reinterpret_cast<uint4*>(wb + 4096)  = S1;                             \
      *reinterpret_cast<uint4*>(wb + 8192)  = S2;                             \
      *reinterpret_cast<uint4*>(wb + 12288) = S3;                             \
    }                                                                         \
    if ((TT) + 2 < NSTEP) ISSUE((TT) + 2);                                    \
    asm volatile("s_waitcnt lgkmcnt(0)" ::: "memory");                        \
    __builtin_amdgcn_s_barrier();                                             \
    asm volatile("" ::: "memory");                                            \
    {                                                                         \
      const char* bA = SMb + (PAR) * 32768;                                   \
      const char* bB = bA + 16384;                                            \
      f16x8 ah[2], al[2];                                                     \
      _Pragma("unroll")                                                       \
      for (int mi = 0; mi < 2; ++mi) {                                        \
        ah[mi] = *reinterpret_cast<const f16x8*>(bA + aOff[mi] + cHi);        \
        al[mi] = *reinterpret_cast<const f16x8*>(bA + aOff[mi] + cLo);        \
      }                                                                       \
      _Pragma("unroll")                                                       \
      for (int ni = 0; ni < 4; ++ni) {                                        \
        f16x8 bh = *reinterpret_cast<const f16x8*>(bB + bOff[ni] + cHi);      \
        f16x8 bl = *reinterpret_cast<const f16x8*>(bB + bOff[ni] + cLo);      \
        _Pragma("unroll")                                                     \
        for (int mi = 0; mi < 2; ++mi) {                                      \
          acc[mi][ni] = __builtin_amdgcn_mfma_f32_16x16x32_f16(ah[mi], bh, acc[mi][ni], 0, 0, 0); \
          acc[mi][ni] = __builtin_amdgcn_mfma_f32_16x16x32_f16(ah[mi], bl, acc[mi][ni], 0, 0, 0); \
          acc[mi][ni] = __builtin_amdgcn_mfma_f32_16x16x32_f16(al[mi], bh, acc[mi][ni], 0, 0, 0); \
        }                                                                     \
      }                                                                       \
    }                                                                         \
  }

  int t = 0;
  for (int jt = jtb; jt < jtb + JT_PER_S; ++jt) {
    const int j0 = jt * 128;
    if (tid < 128) ibS[tid] = g_invB[j0 + tid];

    f32x4 acc[2][4];
#pragma unroll
    for (int mi = 0; mi < 2; ++mi)
#pragma unroll
      for (int ni = 0; ni < 4; ++ni)
#pragma unroll
        for (int q = 0; q < 4; ++q) acc[mi][ni][q] = 0.f;

    for (int g2 = 0; g2 < GPJ / 2; ++g2) {
      KSTEP(0, sa0, sa1, sa2, sa3, issueA, t);   // even step: set A, buf 0
      ++t;
      KSTEP(1, sb0, sb1, sb2, sb3, issueB, t);   // odd step:  set B, buf 1
      ++t;
    }

    // ---- epilogue: scale to cosine sims (C layout: col=fr, row=kq*4+r) ----
    // (batches t+1, t+2 for the next j-tile are in flight under this work)
    float ib[4];
#pragma unroll
    for (int ni = 0; ni < 4; ++ni) ib[ni] = ibS[wc * 64 + ni * 16 + fr];
#pragma unroll
    for (int mi = 0; mi < 2; ++mi)
#pragma unroll
      for (int r = 0; r < 4; ++r) {
        const float iar = iaS[wr * 32 + mi * 16 + kq * 4 + r];
#pragma unroll
        for (int ni = 0; ni < 4; ++ni)
          acc[mi][ni][r] *= iar * ib[ni];
      }

    // ---- row top-2 (reduce over cols: 4 ni in-thread, then 16 fr lanes) ----
#pragma unroll
    for (int mi = 0; mi < 2; ++mi) {
#pragma unroll
      for (int r = 0; r < 4; ++r) {
        const int row = wr * 32 + mi * 16 + kq * 4 + r;
        float v0 = -1e30f, v1 = -1e30f; int id0 = 0x7fffffff, id1 = 0x7fffffff;
#pragma unroll
        for (int ni = 0; ni < 4; ++ni)
          t2_ins(acc[mi][ni][r], j0 + wc * 64 + ni * 16 + fr, v0, id0, v1, id1);
#pragma unroll
        for (int m = 1; m < 16; m <<= 1) {
          float ov0 = __shfl_xor(v0, m), ov1 = __shfl_xor(v1, m);
          int oi0 = __shfl_xor(id0, m), oi1 = __shfl_xor(id1, m);
          t2_ins(ov0, oi0, v0, id0, v1, id1);
          t2_ins(ov1, oi1, v0, id0, v1, id1);
        }
        if (fr == 0) {                      // unique (wave, kq, mi, r) owner
          Top2 tT = rowW[wc][row];
          t2_ins(v0, id0, tT.v0, tT.i0, tT.v1, tT.i1);
          t2_ins(v1, id1, tT.v0, tT.i0, tT.v1, tT.i1);
          rowW[wc][row] = tT;
        }
      }
    }

    // ---- col top-2 (reduce 8 in-thread rows, then across kq groups) ----
#pragma unroll
    for (int ni = 0; ni < 4; ++ni) {
      float v0 = -1e30f, v1 = -1e30f; int id0 = 0x7fffffff, id1 = 0x7fffffff;
#pragma unroll
      for (int mi = 0; mi < 2; ++mi)
#pragma unroll
        for (int r = 0; r < 4; ++r)
          t2_ins(acc[mi][ni][r], i0 + wr * 32 + mi * 16 + kq * 4 + r, v0, id0, v1, id1);
#pragma unroll
      for (int m = 16; m < 64; m <<= 1) {
        float ov0 = __shfl_xor(v0, m), ov1 = __shfl_xor(v1, m);
        int oi0 = __shfl_xor(id0, m), oi1 = __shfl_xor(id1, m);
        t2_ins(ov0, oi0, v0, id0, v1, id1);
        t2_ins(ov1, oi1, v0, id0, v1, id1);
      }
      if (kq == 0) {
        Top2 tT; tT.v0 = v0; tT.v1 = v1; tT.i0 = id0; tT.i1 = id1;
        colW[wr][wc * 64 + ni * 16 + fr] = tT;
      }
    }
    __syncthreads();                        // colW visible (drains in-flight
                                            // prefetch once per j-tile; OK)
    if (tid < 128) {
      Top2 tT = colW[0][tid];
#pragma unroll
      for (int w = 1; w < 4; ++w) {
        Top2 o = colW[w][tid];
        t2_ins(o.v0, o.i0, tT.v0, tT.i0, tT.v1, tT.i1);
        t2_ins(o.v1, o.i1, tT.v0, tT.i0, tT.v1, tT.i1);
      }
      g_cpart[itile][j0 + tid] = tT;
    }
  }
#undef KSTEP

  __syncthreads();
  if (tid < 128) {
    Top2 tT = rowW[0][tid];
    Top2 o  = rowW[1][tid];
    t2_ins(o.v0, o.i0, tT.v0, tT.i0, tT.v1, tT.i1);
    t2_ins(o.v1, o.i1, tT.v0, tT.i0, tT.v1, tT.i1);
    g_rpart[slice][i0 + tid] = tT;
  }
}

// ---------------- kernel 3: merge partials ----------------
__global__ void merge_kernel() {
  int i = blockIdx.x * 256 + threadIdx.x;
  if (i >= N) return;
  {
    float v0 = -1e30f, v1 = -1e30f; int id0 = 0x7fffffff, id1 = 0x7fffffff;
#pragma unroll
    for (int s = 0; s < NS; ++s) {
      Top2 p = g_rpart[s][i];
      t2_ins(p.v0, p.i0, v0, id0, v1, id1);
      t2_ins(p.v1, p.i1, v0, id0, v1, id1);
    }
    float d0 = 2.f - 2.f * v0, d1 = 2.f - 2.f * v1;
    g_nn12[i] = id0; g_r12[i] = d0 / (d1 + 1e-8f); g_sim0[i] = v0;
  }
  {
    float v0 = -1e30f, v1 = -1e30f; int id0 = 0x7fffffff, id1 = 0x7fffffff;
    for (int it = 0; it < NTILE; ++it) {
      Top2 p = g_cpart[it][i];
      t2_ins(p.v0, p.i0, v0, id0, v1, id1);
      t2_ins(p.v1, p.i1, v0, id0, v1, id1);
    }
    float d0 = 2.f - 2.f * v0, d1 = 2.f - 2.f * v1;
    g_nn21[i] = id0; g_r21[i] = d0 / (d1 + 1e-8f);
  }
}

// ---------------- kernel 4: mutual-NN + ratio mask, outputs ----------------
__global__ void finalize_kernel(float* __restrict__ out) {
  int i = blockIdx.x * 256 + threadIdx.x;
  if (i >= N) return;
  int j = g_nn12[i];
  int jc = j < 0 ? 0 : (j >= N ? N - 1 : j);
  bool mask = (g_nn21[jc] == i) && (g_r12[i] <= 0.95f) && (g_r21[jc] <= 0.95f);
  out[i]         = bf16_quant(mask ? g_sim0[i] : 0.f);
  out[N + i]     = bf16_quant((float)j);
  out[2 * N + i] = mask ? 1.f : 0.f;
}

extern "C" void kernel_launch(void* const* d_in, const int* in_sizes, int n_in,
                              void* d_out, int out_size, void* d_ws, size_t ws_size,
                              hipStream_t stream) {
  const float* A = (const float*)d_in[0];  // fp32, channel-major [CH][N]
  const float* B = (const float*)d_in[1];
  (void)d_ws; (void)ws_size;

  prep_kernel<<<dim3(192, 2), 256, 0, stream>>>(A, B);
  sim_top2_mfma<<<dim3(NTILE, NS), 512, 0, stream>>>();
  merge_kernel<<<dim3((N + 255) / 256), 256, 0, stream>>>();
  finalize_kernel<<<dim3((N + 255) / 256), 256, 0, stream>>>((float*)d_out);
}